// Round 5
// baseline (268.276 us; speedup 1.0000x reference)
//
#include <hip/hip_runtime.h>
#include <hip/hip_bf16.h>
#include <hip/hip_fp16.h>

#define CC 256   // input channels
#define OO 256   // output channels
#define HH 64
#define WW 64
#define HWN 4096 // H*W
#define MPB 64   // pixels per block
#define NPB 64   // outputs per block

typedef _Float16 half8 __attribute__((ext_vector_type(8)));
typedef _Float16 half2v __attribute__((ext_vector_type(2)));
typedef float f32x4 __attribute__((ext_vector_type(4)));

__device__ __forceinline__ half2v u2h(unsigned u) {
  half2v h; __builtin_memcpy(&h, &u, 4); return h;
}
__device__ __forceinline__ unsigned h2u(half2v h) {
  unsigned u; __builtin_memcpy(&u, &h, 4); return u;
}
__device__ __forceinline__ unsigned pkdup(float f) {
  _Float16 h = (_Float16)f;
  unsigned short us; __builtin_memcpy(&us, &h, 2);
  return ((unsigned)us << 16) | us;
}
__device__ __forceinline__ unsigned pk2(float a, float b) {
  half2v h = {(_Float16)a, (_Float16)b};
  return h2u(h);
}

// ---------------- transpose x: [N,C,H,W] f32 -> xt [N,H*W,C] fp16 ----------------
__global__ __launch_bounds__(256) void transpose_x_kernel(
    const float* __restrict__ x, _Float16* __restrict__ xt) {
  __shared__ float tile[64][65];
  const int n  = blockIdx.z;
  const int c0 = blockIdx.y * 64;
  const int s0 = blockIdx.x * 64;
  const int tid = threadIdx.x;
  {
    int r  = tid >> 2;
    int sc = (tid & 3) * 16;
    const float* xp = x + ((size_t)(n * CC + c0 + r)) * HWN + s0 + sc;
    float4 f0 = *(const float4*)(xp);
    float4 f1 = *(const float4*)(xp + 4);
    float4 f2 = *(const float4*)(xp + 8);
    float4 f3 = *(const float4*)(xp + 12);
    *(float4*)&tile[r][sc]      = f0;
    *(float4*)&tile[r][sc + 4]  = f1;
    *(float4*)&tile[r][sc + 8]  = f2;
    *(float4*)&tile[r][sc + 12] = f3;
  }
  __syncthreads();
  {
    int s  = tid >> 2;
    int cg = (tid & 3) * 16;
    uint4 u0, u1;
    u0.x = pk2(tile[cg + 0][s],  tile[cg + 1][s]);
    u0.y = pk2(tile[cg + 2][s],  tile[cg + 3][s]);
    u0.z = pk2(tile[cg + 4][s],  tile[cg + 5][s]);
    u0.w = pk2(tile[cg + 6][s],  tile[cg + 7][s]);
    u1.x = pk2(tile[cg + 8][s],  tile[cg + 9][s]);
    u1.y = pk2(tile[cg + 10][s], tile[cg + 11][s]);
    u1.z = pk2(tile[cg + 12][s], tile[cg + 13][s]);
    u1.w = pk2(tile[cg + 14][s], tile[cg + 15][s]);
    _Float16* op = xt + ((size_t)(n * HWN + s0 + s)) * CC + c0 + cg;
    *(uint4*)(op)     = u0;
    *(uint4*)(op + 8) = u1;
  }
}

// ------------- transpose weight: [O,C,3,3] f32 -> wt [9][O][C] fp16 -------------
__global__ __launch_bounds__(256) void transpose_w_kernel(
    const float* __restrict__ w, _Float16* __restrict__ wt) {
  int tid = blockIdx.x * 256 + threadIdx.x;
  int k = tid >> 16;
  int o = (tid >> 8) & 255;
  int c = tid & 255;
  wt[tid] = (_Float16)w[((size_t)o * CC + c) * 9 + k];
}

// ---------------- fused deform-sample + MFMA, pipelined ----------------
// grid: 1024 blocks x 256 thr. Block: 64 px x 64 o. bx>>2 -> pixel group, bx&3 -> o group.
// val_lds fragment-contiguous: frag f=(g*4+mt) at f*512 halfs; lane L at L*8
// holds A[m=mt*16+(L&15)][k-in-chunk=(L>>4)*8+j], chunk g = channels g*32..g*32+31.
__global__ __launch_bounds__(256, 2) void deform_mfma_kernel(
    const _Float16* __restrict__ xt,   // [4][4096][256] fp16
    const _Float16* __restrict__ wt,   // [9][256][256] fp16  ([k][o][c])
    const float* __restrict__ off,
    float* __restrict__ out) {
  __shared__ __align__(16) _Float16 val_lds[2][32 * 512];  // 2 x 32 KB
  __shared__ ushort4 s_po[MPB * 9];   // clamped flat corner offsets
  __shared__ uint4   s_pw[MPB * 9];   // dup-packed half2 bilinear weights

  const int tid  = threadIdx.x;
  const int lane = tid & 63;
  const int wv   = tid >> 6;
  const int n15  = lane & 15;
  const int quad = lane >> 4;
  const int mh   = wv >> 1;   // m-half: pixels mh*32..mh*32+31
  const int nh   = wv & 1;    // n-half: outputs nh*32..nh*32+31

  const int bx    = blockIdx.x;
  const int pg    = (bx >> 2) * MPB;
  const int nb    = pg >> 12;
  const int hw0   = pg & (HWN - 1);
  const int obase = (bx & 3) * NPB;

  // ---- precompute per-(pixel,tap) sampling params ----
  for (int e = tid; e < MPB * 9; e += 256) {
    int p = e / 9;
    int k = e - p * 9;
    int hw = hw0 + p;
    int h = hw >> 6, w = hw & 63;
    size_t ob = ((size_t)(nb * HWN + hw)) * 18 + 2 * k;
    float2 d = *(const float2*)(off + ob);
    float py = (float)(h + k / 3 - 1) + d.x;
    float px = (float)(w + k % 3 - 1) + d.y;
    float fy = floorf(py), fx = floorf(px);
    int iy = (int)fy, ix = (int)fx;
    float wy = py - fy, wx = px - fx;
    float my0 = ((unsigned)iy       < (unsigned)HH) ? 1.f : 0.f;
    float my1 = ((unsigned)(iy + 1) < (unsigned)HH) ? 1.f : 0.f;
    float mx0 = ((unsigned)ix       < (unsigned)WW) ? 1.f : 0.f;
    float mx1 = ((unsigned)(ix + 1) < (unsigned)WW) ? 1.f : 0.f;
    int iy0 = min(max(iy, 0), HH - 1), iy1 = min(max(iy + 1, 0), HH - 1);
    int ix0 = min(max(ix, 0), WW - 1), ix1 = min(max(ix + 1, 0), WW - 1);
    s_po[e] = make_ushort4((unsigned short)(iy0 * WW + ix0),
                           (unsigned short)(iy0 * WW + ix1),
                           (unsigned short)(iy1 * WW + ix0),
                           (unsigned short)(iy1 * WW + ix1));
    s_pw[e] = make_uint4(pkdup((1.f - wy) * (1.f - wx) * my0 * mx0),
                         pkdup((1.f - wy) * wx         * my0 * mx1),
                         pkdup(wy         * (1.f - wx) * my1 * mx0),
                         pkdup(wy         * wx         * my1 * mx1));
  }
  __syncthreads();   // params visible before prologue sampling

  f32x4 acc[2][2];
#pragma unroll
  for (int a = 0; a < 2; ++a)
#pragma unroll
    for (int b = 0; b < 2; ++b) acc[a][b] = (f32x4){0.f, 0.f, 0.f, 0.f};

  const _Float16* xb = xt + (size_t)nb * HWN * CC;
  const int p = wv * 16 + n15;   // this thread's pixel for sampling (m-tile = wv)

  // sample tap k into buf: thread covers pixel p, channels g*32+quad*8 for g=0..7
  auto SAMPLE = [&](int k, _Float16* buf) {
    int idx = p * 9 + k;
    ushort4 o4 = s_po[idx];
    uint4   wd = s_pw[idx];
    half2v w00 = u2h(wd.x), w01 = u2h(wd.y), w10 = u2h(wd.z), w11 = u2h(wd.w);
    const _Float16* p00 = xb + (size_t)o4.x * CC + quad * 8;
    const _Float16* p01 = xb + (size_t)o4.y * CC + quad * 8;
    const _Float16* p10 = xb + (size_t)o4.z * CC + quad * 8;
    const _Float16* p11 = xb + (size_t)o4.w * CC + quad * 8;
#pragma unroll
    for (int g = 0; g < 8; ++g) {
      uint4 v00 = *(const uint4*)(p00 + g * 32);
      uint4 v01 = *(const uint4*)(p01 + g * 32);
      uint4 v10 = *(const uint4*)(p10 + g * 32);
      uint4 v11 = *(const uint4*)(p11 + g * 32);
      uint4 r;
      r.x = h2u(u2h(v00.x) * w00 + u2h(v01.x) * w01 + u2h(v10.x) * w10 + u2h(v11.x) * w11);
      r.y = h2u(u2h(v00.y) * w00 + u2h(v01.y) * w01 + u2h(v10.y) * w10 + u2h(v11.y) * w11);
      r.z = h2u(u2h(v00.z) * w00 + u2h(v01.z) * w01 + u2h(v10.z) * w10 + u2h(v11.z) * w11);
      r.w = h2u(u2h(v00.w) * w00 + u2h(v01.w) * w01 + u2h(v10.w) * w10 + u2h(v11.w) * w11);
      *(uint4*)(buf + (g * 4 + wv) * 512 + lane * 8) = r;   // ds_write_b128 linear
    }
  };

  SAMPLE(0, val_lds[0]);

#pragma unroll 1
  for (int k = 0; k < 9; ++k) {
    // ---- B prefetch into registers (latency hidden behind sampling) ----
    const _Float16* wk = wt + ((size_t)k * OO + obase + nh * 32 + n15) * CC + quad * 8;
    half8 breg[16];
#pragma unroll
    for (int g = 0; g < 8; ++g) {
      breg[g * 2 + 0] = *(const half8*)(wk + g * 32);
      breg[g * 2 + 1] = *(const half8*)(wk + 16 * CC + g * 32);
    }

    if (k < 8) SAMPLE(k + 1, val_lds[(k + 1) & 1]);

    __syncthreads();   // buf[k&1] (written prev iter / prologue) visible

    const _Float16* vb = val_lds[k & 1];
#pragma unroll
    for (int g = 0; g < 8; ++g) {
      half8 a0 = *(const half8*)(vb + (g * 4 + mh * 2 + 0) * 512 + lane * 8);
      half8 a1 = *(const half8*)(vb + (g * 4 + mh * 2 + 1) * 512 + lane * 8);
      acc[0][0] = __builtin_amdgcn_mfma_f32_16x16x32_f16(a0, breg[g * 2 + 0], acc[0][0], 0, 0, 0);
      acc[0][1] = __builtin_amdgcn_mfma_f32_16x16x32_f16(a0, breg[g * 2 + 1], acc[0][1], 0, 0, 0);
      acc[1][0] = __builtin_amdgcn_mfma_f32_16x16x32_f16(a1, breg[g * 2 + 0], acc[1][0], 0, 0, 0);
      acc[1][1] = __builtin_amdgcn_mfma_f32_16x16x32_f16(a1, breg[g * 2 + 1], acc[1][1], 0, 0, 0);
    }

    __syncthreads();   // MFMA reads done before next tap overwrites buf[k&1]
  }

  // ---- epilogue: D: col=lane&15 -> o, row=quad*4+reg -> pixel ----
#pragma unroll
  for (int mt = 0; mt < 2; ++mt)
#pragma unroll
    for (int nt = 0; nt < 2; ++nt) {
      int o  = obase + nh * 32 + nt * 16 + n15;
      int px = hw0 + (mh * 2 + mt) * 16 + quad * 4;
      *(f32x4*)(out + ((size_t)nb * OO + o) * HWN + px) = acc[mt][nt];
    }
}

extern "C" void kernel_launch(void* const* d_in, const int* in_sizes, int n_in,
                              void* d_out, int out_size, void* d_ws, size_t ws_size,
                              hipStream_t stream) {
  const float* x   = (const float*)d_in[0];   // [4,256,64,64]
  const float* off = (const float*)d_in[1];   // [4,4096,18]
  const float* w   = (const float*)d_in[2];   // [256,256,3,3]
  float* out = (float*)d_out;                 // [4,256,64,64]

  _Float16* wt = (_Float16*)d_ws;             // 589824 fp16
  _Float16* xt = wt + 589824;                 // 4194304 fp16

  transpose_w_kernel<<<2304, 256, 0, stream>>>(w, wt);
  dim3 gx(HWN / 64, CC / 64, 4);
  transpose_x_kernel<<<gx, 256, 0, stream>>>(x, xt);
  deform_mfma_kernel<<<(4 * HWN / MPB) * (OO / NPB), 256, 0, stream>>>(xt, wt, off, out);
}

// Round 6
// 141.366 us; speedup vs baseline: 1.8977x; 1.8977x over previous
//
#include <hip/hip_runtime.h>
#include <hip/hip_fp16.h>

#define CC 256   // input channels
#define OO 256   // output channels
#define HH 64
#define WW 64
#define HWN 4096 // H*W
#define MPB 64   // pixels per block
#define NPB 128  // outputs per block
#define KCH 128  // c-chunk for weight staging
#define VST 264  // val_lds row stride (halfs)
#define WST 136  // w_lds row stride (halfs)

typedef _Float16 half8 __attribute__((ext_vector_type(8)));
typedef _Float16 half2v __attribute__((ext_vector_type(2)));
typedef float f32x4 __attribute__((ext_vector_type(4)));

__device__ __forceinline__ half2v u2h(unsigned u) {
  half2v h; __builtin_memcpy(&h, &u, 4); return h;
}
__device__ __forceinline__ unsigned h2u(half2v h) {
  unsigned u; __builtin_memcpy(&u, &h, 4); return u;
}
__device__ __forceinline__ unsigned short f2h(float f) {
  _Float16 h = (_Float16)f;
  unsigned short us; __builtin_memcpy(&us, &h, 2);
  return us;
}
__device__ __forceinline__ unsigned dupu(unsigned short us) {
  return ((unsigned)us << 16) | us;
}
__device__ __forceinline__ unsigned pk2(float a, float b) {
  half2v h = {(_Float16)a, (_Float16)b};
  return h2u(h);
}

// ---------- fused prep: x [N,C,H,W] f32 -> xt [N,HW,C] fp16 ; w -> wt [9][O][C] fp16 ----------
__global__ __launch_bounds__(256) void prep_kernel(
    const float* __restrict__ x, const float* __restrict__ w,
    _Float16* __restrict__ xt, _Float16* __restrict__ wt) {
  __shared__ float tile[64][65];
  const int bid = blockIdx.x;
  const int tid = threadIdx.x;
  if (bid < 1024) {
    const int n  = bid >> 8;
    const int c0 = ((bid >> 6) & 3) * 64;
    const int s0 = (bid & 63) * 64;
    {
      int r  = tid >> 2;
      int sc = (tid & 3) * 16;
      const float* xp = x + ((size_t)(n * CC + c0 + r)) * HWN + s0 + sc;
      *(float4*)&tile[r][sc]      = *(const float4*)(xp);
      *(float4*)&tile[r][sc + 4]  = *(const float4*)(xp + 4);
      *(float4*)&tile[r][sc + 8]  = *(const float4*)(xp + 8);
      *(float4*)&tile[r][sc + 12] = *(const float4*)(xp + 12);
    }
    __syncthreads();
    {
      int s  = tid >> 2;
      int cg = (tid & 3) * 16;
      uint4 u0, u1;
      u0.x = pk2(tile[cg + 0][s],  tile[cg + 1][s]);
      u0.y = pk2(tile[cg + 2][s],  tile[cg + 3][s]);
      u0.z = pk2(tile[cg + 4][s],  tile[cg + 5][s]);
      u0.w = pk2(tile[cg + 6][s],  tile[cg + 7][s]);
      u1.x = pk2(tile[cg + 8][s],  tile[cg + 9][s]);
      u1.y = pk2(tile[cg + 10][s], tile[cg + 11][s]);
      u1.z = pk2(tile[cg + 12][s], tile[cg + 13][s]);
      u1.w = pk2(tile[cg + 14][s], tile[cg + 15][s]);
      _Float16* op = xt + ((size_t)(n * HWN + s0 + s)) * CC + c0 + cg;
      *(uint4*)(op)     = u0;
      *(uint4*)(op + 8) = u1;
    }
  } else {
    int e = (bid - 1024) * 256 + tid;   // 0 .. 589823
    int k = e >> 16;
    int o = (e >> 8) & 255;
    int c = e & 255;
    wt[e] = (_Float16)w[((size_t)o * CC + c) * 9 + k];
  }
}

// ---------------- fused deform-sample (fp16 packed) + MFMA GEMM ----------------
// grid 512 x 256 thr. Block: 64 px x 128 o. bx>>1 -> pixel group, bx&1 -> o-half.
__global__ __launch_bounds__(256, 2) void deform_mfma_kernel(
    const _Float16* __restrict__ xt,   // [4][4096][256] fp16
    const _Float16* __restrict__ wt,   // [9][256][256] fp16 ([k][o][c])
    const float* __restrict__ off,
    float* __restrict__ out) {
  __shared__ __align__(16) _Float16 val_lds[MPB * VST];   // 33792 B [p][c]
  __shared__ __align__(16) _Float16 w_lds[NPB * WST];     // 34816 B [o][c-in-chunk]
  __shared__ ushort4 s_po[MPB * 9];   // clamped flat corner row offsets (4.5 KB)
  __shared__ ushort4 s_pw[MPB * 9];   // fp16 bilinear weights (4.5 KB)

  const int tid  = threadIdx.x;
  const int lane = tid & 63;
  const int wv   = tid >> 6;
  const int n15  = lane & 15;
  const int quad = lane >> 4;

  const int bx    = blockIdx.x;
  const int pg    = (bx >> 1) * MPB;
  const int nb    = pg >> 12;
  const int hw0   = pg & (HWN - 1);
  const int obase = (bx & 1) * NPB;

  // ---- precompute per-(pixel,tap) sampling params ----
  for (int e = tid; e < MPB * 9; e += 256) {
    int p = e / 9;
    int k = e - p * 9;
    int hw = hw0 + p;
    int h = hw >> 6, w = hw & 63;
    size_t ob = ((size_t)(nb * HWN + hw)) * 18 + 2 * k;
    float2 d = *(const float2*)(off + ob);
    float py = (float)(h + k / 3 - 1) + d.x;
    float px = (float)(w + k % 3 - 1) + d.y;
    float fy = floorf(py), fx = floorf(px);
    int iy = (int)fy, ix = (int)fx;
    float wy = py - fy, wx = px - fx;
    float my0 = ((unsigned)iy       < (unsigned)HH) ? 1.f : 0.f;
    float my1 = ((unsigned)(iy + 1) < (unsigned)HH) ? 1.f : 0.f;
    float mx0 = ((unsigned)ix       < (unsigned)WW) ? 1.f : 0.f;
    float mx1 = ((unsigned)(ix + 1) < (unsigned)WW) ? 1.f : 0.f;
    int iy0 = min(max(iy, 0), HH - 1), iy1 = min(max(iy + 1, 0), HH - 1);
    int ix0 = min(max(ix, 0), WW - 1), ix1 = min(max(ix + 1, 0), WW - 1);
    s_po[e] = make_ushort4((unsigned short)(iy0 * WW + ix0),
                           (unsigned short)(iy0 * WW + ix1),
                           (unsigned short)(iy1 * WW + ix0),
                           (unsigned short)(iy1 * WW + ix1));
    s_pw[e] = make_ushort4(f2h((1.f - wy) * (1.f - wx) * my0 * mx0),
                           f2h((1.f - wy) * wx         * my0 * mx1),
                           f2h(wy         * (1.f - wx) * my1 * mx0),
                           f2h(wy         * wx         * my1 * mx1));
  }

  f32x4 acc[4][2];
#pragma unroll
  for (int a = 0; a < 4; ++a)
#pragma unroll
    for (int b = 0; b < 2; ++b) acc[a][b] = (f32x4){0.f, 0.f, 0.f, 0.f};

  const _Float16* xb = xt + (size_t)nb * HWN * CC;
  const int j = lane & 31;            // channel chunk j*8..j*8+7
  const int ph = lane >> 5;           // which pixel of the pair

  for (int k = 0; k < 9; ++k) {
    __syncthreads();   // prev tap A-reads done; (k==0) params visible

    // ---- sample tap k: 2 pixels per wave-iter, contiguous 512B row loads ----
#pragma unroll
    for (int i = 0; i < 8; ++i) {
      int p = i * 8 + wv * 2 + ph;
      int idx = p * 9 + k;
      ushort4 o4 = s_po[idx];
      ushort4 hw4 = s_pw[idx];
      half2v w00 = u2h(dupu(hw4.x)), w01 = u2h(dupu(hw4.y));
      half2v w10 = u2h(dupu(hw4.z)), w11 = u2h(dupu(hw4.w));
      const _Float16* cb = xb + (size_t)j * 8;
      uint4 v00 = *(const uint4*)(cb + (size_t)o4.x * CC);
      uint4 v01 = *(const uint4*)(cb + (size_t)o4.y * CC);
      uint4 v10 = *(const uint4*)(cb + (size_t)o4.z * CC);
      uint4 v11 = *(const uint4*)(cb + (size_t)o4.w * CC);
      uint4 r;
      r.x = h2u(u2h(v00.x) * w00 + u2h(v01.x) * w01 + u2h(v10.x) * w10 + u2h(v11.x) * w11);
      r.y = h2u(u2h(v00.y) * w00 + u2h(v01.y) * w01 + u2h(v10.y) * w10 + u2h(v11.y) * w11);
      r.z = h2u(u2h(v00.z) * w00 + u2h(v01.z) * w01 + u2h(v10.z) * w10 + u2h(v11.z) * w11);
      r.w = h2u(u2h(v00.w) * w00 + u2h(v01.w) * w01 + u2h(v10.w) * w10 + u2h(v11.w) * w11);
      *(uint4*)(val_lds + p * VST + j * 8) = r;   // consecutive 16B per half-wave
    }

    // ---- GEMM tap k over two 128-channel chunks ----
    for (int cc = 0; cc < CC / KCH; ++cc) {
      __syncthreads();   // prev chunk B-reads done
      {
        // stage 128 o x 128 c fp16 = 32 KB; thread copies 2 x 32c = 2 x 4 uint4
        int q = tid & 3;
        int orow = tid >> 2;             // 0..63
#pragma unroll
        for (int rr = 0; rr < 2; ++rr) {
          int o = rr * 64 + orow;
          const uint4* src = (const uint4*)(wt + ((size_t)(k * OO + obase + o)) * CC + cc * KCH + q * 32);
          uint4* dst = (uint4*)(w_lds + o * WST + q * 32);
          dst[0] = src[0];
          dst[1] = src[1];
          dst[2] = src[2];
          dst[3] = src[3];
        }
      }
      __syncthreads();   // w_lds staged; also orders val_lds writes before A-reads (cc==0)
#pragma unroll
      for (int ks = 0; ks < 4; ++ks) {
        int cbase = cc * KCH + ks * 32;
        half8 afr[4], bfr[2];
#pragma unroll
        for (int mt = 0; mt < 4; ++mt)
          afr[mt] = *(const half8*)(val_lds + (mt * 16 + n15) * VST + cbase + quad * 8);
#pragma unroll
        for (int nt = 0; nt < 2; ++nt)
          bfr[nt] = *(const half8*)(w_lds + (wv * 32 + nt * 16 + n15) * WST + ks * 32 + quad * 8);
#pragma unroll
        for (int mt = 0; mt < 4; ++mt)
#pragma unroll
          for (int nt = 0; nt < 2; ++nt)
            acc[mt][nt] = __builtin_amdgcn_mfma_f32_16x16x32_f16(
                afr[mt], bfr[nt], acc[mt][nt], 0, 0, 0);
      }
    }
  }

  // ---- epilogue: D: col=lane&15 -> o, row=quad*4+reg -> pixel ----
#pragma unroll
  for (int mt = 0; mt < 4; ++mt)
#pragma unroll
    for (int nt = 0; nt < 2; ++nt) {
      int o  = obase + wv * 32 + nt * 16 + n15;
      int px = hw0 + mt * 16 + quad * 4;
      *(f32x4*)(out + ((size_t)nb * OO + o) * HWN + px) = acc[mt][nt];
    }
}

extern "C" void kernel_launch(void* const* d_in, const int* in_sizes, int n_in,
                              void* d_out, int out_size, void* d_ws, size_t ws_size,
                              hipStream_t stream) {
  const float* x   = (const float*)d_in[0];   // [4,256,64,64]
  const float* off = (const float*)d_in[1];   // [4,4096,18]
  const float* w   = (const float*)d_in[2];   // [256,256,3,3]
  float* out = (float*)d_out;                 // [4,256,64,64]

  _Float16* wt = (_Float16*)d_ws;             // 589824 fp16
  _Float16* xt = wt + 589824;                 // 4194304 fp16

  prep_kernel<<<1024 + 2304, 256, 0, stream>>>(x, w, xt, wt);
  deform_mfma_kernel<<<(4 * HWN / MPB) * (OO / NPB), 256, 0, stream>>>(xt, wt, off, out);
}

// Round 7
// 127.515 us; speedup vs baseline: 2.1039x; 1.1086x over previous
//
#include <hip/hip_runtime.h>
#include <hip/hip_fp16.h>

#define CC 256   // input channels
#define OO 256   // output channels
#define HH 64
#define WW 64
#define HWN 4096 // H*W
#define MPB 64   // pixels per block
#define NPB 128  // outputs per block
#define KCH 128  // c-chunk for weight staging
#define VST 264  // val_lds row stride (halfs)
#define WST 136  // w_lds row stride (halfs)

typedef _Float16 half8 __attribute__((ext_vector_type(8)));
typedef _Float16 half2v __attribute__((ext_vector_type(2)));
typedef float f32x4 __attribute__((ext_vector_type(4)));

__device__ __forceinline__ half2v u2h(unsigned u) {
  half2v h; __builtin_memcpy(&h, &u, 4); return h;
}
__device__ __forceinline__ unsigned h2u(half2v h) {
  unsigned u; __builtin_memcpy(&u, &h, 4); return u;
}
__device__ __forceinline__ unsigned short f2h(float f) {
  _Float16 h = (_Float16)f;
  unsigned short us; __builtin_memcpy(&us, &h, 2);
  return us;
}
__device__ __forceinline__ unsigned dupu(unsigned short us) {
  return ((unsigned)us << 16) | us;
}
__device__ __forceinline__ unsigned pk2(float a, float b) {
  half2v h = {(_Float16)a, (_Float16)b};
  return h2u(h);
}

// ---------- fused prep: x [N,C,H,W] f32 -> xt [N,HW,C] fp16 ; w -> wt [9][O][C] fp16 ----------
__global__ __launch_bounds__(256) void prep_kernel(
    const float* __restrict__ x, const float* __restrict__ w,
    _Float16* __restrict__ xt, _Float16* __restrict__ wt) {
  __shared__ float tile[64][65];
  const int bid = blockIdx.x;
  const int tid = threadIdx.x;
  if (bid < 1024) {
    const int n  = bid >> 8;
    const int c0 = ((bid >> 6) & 3) * 64;
    const int s0 = (bid & 63) * 64;
    {
      int r  = tid >> 2;
      int sc = (tid & 3) * 16;
      const float* xp = x + ((size_t)(n * CC + c0 + r)) * HWN + s0 + sc;
      *(float4*)&tile[r][sc]      = *(const float4*)(xp);
      *(float4*)&tile[r][sc + 4]  = *(const float4*)(xp + 4);
      *(float4*)&tile[r][sc + 8]  = *(const float4*)(xp + 8);
      *(float4*)&tile[r][sc + 12] = *(const float4*)(xp + 12);
    }
    __syncthreads();
    {
      int s  = tid >> 2;
      int cg = (tid & 3) * 16;
      uint4 u0, u1;
      u0.x = pk2(tile[cg + 0][s],  tile[cg + 1][s]);
      u0.y = pk2(tile[cg + 2][s],  tile[cg + 3][s]);
      u0.z = pk2(tile[cg + 4][s],  tile[cg + 5][s]);
      u0.w = pk2(tile[cg + 6][s],  tile[cg + 7][s]);
      u1.x = pk2(tile[cg + 8][s],  tile[cg + 9][s]);
      u1.y = pk2(tile[cg + 10][s], tile[cg + 11][s]);
      u1.z = pk2(tile[cg + 12][s], tile[cg + 13][s]);
      u1.w = pk2(tile[cg + 14][s], tile[cg + 15][s]);
      _Float16* op = xt + ((size_t)(n * HWN + s0 + s)) * CC + c0 + cg;
      *(uint4*)(op)     = u0;
      *(uint4*)(op + 8) = u1;
    }
  } else {
    int e = (bid - 1024) * 256 + tid;   // 0 .. 589823
    int k = e >> 16;
    int o = (e >> 8) & 255;
    int c = e & 255;
    wt[e] = (_Float16)w[((size_t)o * CC + c) * 9 + k];
  }
}

// ---------------- fused deform-sample (fp16 packed) + MFMA GEMM ----------------
// grid 512 x 256 thr. Block: 64 px x 128 o.
// XCD-aware decode (XCD ~ bx%8, 8 XCDs x 64 slots): each XCD works on ONE image n
//   nb = (bx&7)>>1, o-half = bx&1, pixel group = bx>>3
// -> per-XCD L2 working set = 2.1 MB xt slice + 1.18 MB wt < 4 MiB.
__global__ __launch_bounds__(256, 2) void deform_mfma_kernel(
    const _Float16* __restrict__ xt,   // [4][4096][256] fp16
    const _Float16* __restrict__ wt,   // [9][256][256] fp16 ([k][o][c])
    const float* __restrict__ off,
    float* __restrict__ out) {
  __shared__ __align__(16) _Float16 val_lds[MPB * VST];   // 33792 B [p][c]
  __shared__ __align__(16) _Float16 w_lds[NPB * WST];     // 34816 B [o][c-in-chunk]
  __shared__ ushort4 s_po[MPB * 9];   // clamped flat corner row offsets
  __shared__ ushort4 s_pw[MPB * 9];   // fp16 bilinear weights

  const int tid  = threadIdx.x;
  const int lane = tid & 63;
  const int wv   = tid >> 6;
  const int n15  = lane & 15;
  const int quad = lane >> 4;

  const int bx    = blockIdx.x;
  const int nb    = (bx & 7) >> 1;          // image: constant per XCD
  const int hw0   = (bx >> 3) * MPB;        // pixel group within image
  const int obase = (bx & 1) * NPB;         // output half

  // ---- precompute per-(pixel,tap) sampling params ----
  for (int e = tid; e < MPB * 9; e += 256) {
    int p = e / 9;
    int k = e - p * 9;
    int hw = hw0 + p;
    int h = hw >> 6, w = hw & 63;
    size_t ob = ((size_t)(nb * HWN + hw)) * 18 + 2 * k;
    float2 d = *(const float2*)(off + ob);
    float py = (float)(h + k / 3 - 1) + d.x;
    float px = (float)(w + k % 3 - 1) + d.y;
    float fy = floorf(py), fx = floorf(px);
    int iy = (int)fy, ix = (int)fx;
    float wy = py - fy, wx = px - fx;
    float my0 = ((unsigned)iy       < (unsigned)HH) ? 1.f : 0.f;
    float my1 = ((unsigned)(iy + 1) < (unsigned)HH) ? 1.f : 0.f;
    float mx0 = ((unsigned)ix       < (unsigned)WW) ? 1.f : 0.f;
    float mx1 = ((unsigned)(ix + 1) < (unsigned)WW) ? 1.f : 0.f;
    int iy0 = min(max(iy, 0), HH - 1), iy1 = min(max(iy + 1, 0), HH - 1);
    int ix0 = min(max(ix, 0), WW - 1), ix1 = min(max(ix + 1, 0), WW - 1);
    s_po[e] = make_ushort4((unsigned short)(iy0 * WW + ix0),
                           (unsigned short)(iy0 * WW + ix1),
                           (unsigned short)(iy1 * WW + ix0),
                           (unsigned short)(iy1 * WW + ix1));
    s_pw[e] = make_ushort4(f2h((1.f - wy) * (1.f - wx) * my0 * mx0),
                           f2h((1.f - wy) * wx         * my0 * mx1),
                           f2h(wy         * (1.f - wx) * my1 * mx0),
                           f2h(wy         * wx         * my1 * mx1));
  }

  f32x4 acc[4][2];
#pragma unroll
  for (int a = 0; a < 4; ++a)
#pragma unroll
    for (int b = 0; b < 2; ++b) acc[a][b] = (f32x4){0.f, 0.f, 0.f, 0.f};

  const _Float16* xb = xt + (size_t)nb * HWN * CC;
  const int j = lane & 31;            // channel chunk j*8..j*8+7
  const int ph = lane >> 5;           // which pixel of the pair

  for (int k = 0; k < 9; ++k) {
    __syncthreads();   // prev tap A-reads done; (k==0) params visible

    // ---- sample tap k: 2 pixels per wave-iter, contiguous 512B row loads ----
#pragma unroll
    for (int i = 0; i < 8; ++i) {
      int p = i * 8 + wv * 2 + ph;
      int idx = p * 9 + k;
      ushort4 o4 = s_po[idx];
      ushort4 hw4 = s_pw[idx];
      half2v w00 = u2h(dupu(hw4.x)), w01 = u2h(dupu(hw4.y));
      half2v w10 = u2h(dupu(hw4.z)), w11 = u2h(dupu(hw4.w));
      const _Float16* cb = xb + (size_t)j * 8;
      uint4 v00 = *(const uint4*)(cb + (size_t)o4.x * CC);
      uint4 v01 = *(const uint4*)(cb + (size_t)o4.y * CC);
      uint4 v10 = *(const uint4*)(cb + (size_t)o4.z * CC);
      uint4 v11 = *(const uint4*)(cb + (size_t)o4.w * CC);
      uint4 r;
      r.x = h2u(u2h(v00.x) * w00 + u2h(v01.x) * w01 + u2h(v10.x) * w10 + u2h(v11.x) * w11);
      r.y = h2u(u2h(v00.y) * w00 + u2h(v01.y) * w01 + u2h(v10.y) * w10 + u2h(v11.y) * w11);
      r.z = h2u(u2h(v00.z) * w00 + u2h(v01.z) * w01 + u2h(v10.z) * w10 + u2h(v11.z) * w11);
      r.w = h2u(u2h(v00.w) * w00 + u2h(v01.w) * w01 + u2h(v10.w) * w10 + u2h(v11.w) * w11);
      *(uint4*)(val_lds + p * VST + j * 8) = r;   // consecutive 16B per half-wave
    }

    // ---- GEMM tap k over two 128-channel chunks ----
    for (int cc = 0; cc < CC / KCH; ++cc) {
      __syncthreads();   // prev chunk B-reads done
      {
        // stage 128 o x 128 c fp16 = 32 KB; thread copies 2 x 32c = 2 x 4 uint4
        int q = tid & 3;
        int orow = tid >> 2;             // 0..63
#pragma unroll
        for (int rr = 0; rr < 2; ++rr) {
          int o = rr * 64 + orow;
          const uint4* src = (const uint4*)(wt + ((size_t)(k * OO + obase + o)) * CC + cc * KCH + q * 32);
          uint4* dst = (uint4*)(w_lds + o * WST + q * 32);
          dst[0] = src[0];
          dst[1] = src[1];
          dst[2] = src[2];
          dst[3] = src[3];
        }
      }
      __syncthreads();   // w_lds staged; also orders val_lds writes before A-reads (cc==0)
#pragma unroll
      for (int ks = 0; ks < 4; ++ks) {
        int cbase = cc * KCH + ks * 32;
        half8 afr[4], bfr[2];
#pragma unroll
        for (int mt = 0; mt < 4; ++mt)
          afr[mt] = *(const half8*)(val_lds + (mt * 16 + n15) * VST + cbase + quad * 8);
#pragma unroll
        for (int nt = 0; nt < 2; ++nt)
          bfr[nt] = *(const half8*)(w_lds + (wv * 32 + nt * 16 + n15) * WST + ks * 32 + quad * 8);
#pragma unroll
        for (int mt = 0; mt < 4; ++mt)
#pragma unroll
          for (int nt = 0; nt < 2; ++nt)
            acc[mt][nt] = __builtin_amdgcn_mfma_f32_16x16x32_f16(
                afr[mt], bfr[nt], acc[mt][nt], 0, 0, 0);
      }
    }
  }

  // ---- epilogue: D: col=lane&15 -> o, row=quad*4+reg -> pixel ----
#pragma unroll
  for (int mt = 0; mt < 4; ++mt)
#pragma unroll
    for (int nt = 0; nt < 2; ++nt) {
      int o  = obase + wv * 32 + nt * 16 + n15;
      int px = hw0 + mt * 16 + quad * 4;
      *(f32x4*)(out + ((size_t)nb * OO + o) * HWN + px) = acc[mt][nt];
    }
}

extern "C" void kernel_launch(void* const* d_in, const int* in_sizes, int n_in,
                              void* d_out, int out_size, void* d_ws, size_t ws_size,
                              hipStream_t stream) {
  const float* x   = (const float*)d_in[0];   // [4,256,64,64]
  const float* off = (const float*)d_in[1];   // [4,4096,18]
  const float* w   = (const float*)d_in[2];   // [256,256,3,3]
  float* out = (float*)d_out;                 // [4,256,64,64]

  _Float16* wt = (_Float16*)d_ws;             // 589824 fp16
  _Float16* xt = wt + 589824;                 // 4194304 fp16

  prep_kernel<<<1024 + 2304, 256, 0, stream>>>(x, w, xt, wt);
  deform_mfma_kernel<<<(4 * HWN / MPB) * (OO / NPB), 256, 0, stream>>>(xt, wt, off, out);
}